// Round 1
// baseline (750.787 us; speedup 1.0000x reference)
//
#include <hip/hip_runtime.h>

typedef __bf16 bf16_t;
typedef __attribute__((ext_vector_type(8))) __bf16 bf16x8;
typedef __attribute__((ext_vector_type(4))) float f32x4;

#define NH   8
#define DH   64
#define DD   512
#define NPIX 65536   // 256*256

__device__ __forceinline__ unsigned short f2bf(float f) {
  unsigned int u = __builtin_bit_cast(unsigned int, f);
  u += 0x7fffu + ((u >> 16) & 1u);
  return (unsigned short)(u >> 16);
}
__device__ __forceinline__ float bf2f(unsigned short b) {
  return __builtin_bit_cast(float, ((unsigned int)b) << 16);
}

__device__ __forceinline__ void gload_lds16(const void* g, void* l) {
  __builtin_amdgcn_global_load_lds(
      (const __attribute__((address_space(1))) void*)(uintptr_t)g,
      (__attribute__((address_space(3))) void*)(uintptr_t)l, 16, 0, 0);
}

// ---------------- elementwise fp32 -> bf16 convert (weights) ----------------
__global__ __launch_bounds__(256) void k_cvt(const float* __restrict__ in,
                                             unsigned short* __restrict__ out, int n4) {
  int i = blockIdx.x * 256 + threadIdx.x;
  if (i >= n4) return;
  float4 v = ((const float4*)in)[i];
  ushort4 o; o.x = f2bf(v.x); o.y = f2bf(v.y); o.z = f2bf(v.z); o.w = f2bf(v.w);
  ((ushort4*)out)[i] = o;
}

// ------------- x [512][65536] f32 -> x^T [65536][512] bf16 ------------------
__global__ __launch_bounds__(256) void k_cvt_transpose(const float* __restrict__ x,
                                                       unsigned short* __restrict__ xt) {
  __shared__ unsigned short Xs[64 * 68];
  int p0 = blockIdx.x * 64, c0 = blockIdx.y * 64;
  int t = threadIdx.x;
  for (int rep = 0; rep < 4; ++rep) {
    int f = rep * 256 + t, i = f >> 4, jj = f & 15;
    float4 v = *(const float4*)(x + (size_t)(c0 + i) * NPIX + p0 + jj * 4);
    ushort4 o; o.x = f2bf(v.x); o.y = f2bf(v.y); o.z = f2bf(v.z); o.w = f2bf(v.w);
    *(ushort4*)(Xs + i * 68 + jj * 4) = o;
  }
  __syncthreads();
  int j = t >> 2, q = t & 3;
  unsigned short* dst = xt + (size_t)(p0 + j) * DD + c0 + q * 16;
  for (int h2 = 0; h2 < 2; ++h2) {
    union { unsigned short u[8]; uint4 v; } pk;
    for (int cc = 0; cc < 8; ++cc) pk.u[cc] = Xs[(q * 16 + h2 * 8 + cc) * 68 + j];
    *(uint4*)(dst + h2 * 8) = pk.v;
  }
}

// ---------------- GEMM: C[1536][65536] = W[1536][512] @ X + b ---------------
// A: W bf16 [M][K] row-major. Bt: X^T bf16 [N][K] row-major.
// Output: rows 0..1023 (q,k) written TRANSPOSED into qk_t[p][1024];
//         rows 1024..1535 (v) written natural into v_nat[d][p].
__global__ __launch_bounds__(256) void k_gemm(const unsigned short* __restrict__ A,
                                              const unsigned short* __restrict__ Bt,
                                              const float* __restrict__ bias,
                                              unsigned short* __restrict__ qk_t,
                                              unsigned short* __restrict__ v_nat) {
  __shared__ unsigned short As[128 * 32];
  __shared__ unsigned short Bs[128 * 32];
  __shared__ unsigned short Ct[128 * 136];
  int tid = threadIdx.x, lane = tid & 63, wave = tid >> 6;
  int lr = lane & 15, lq = lane >> 4;
  int M0 = blockIdx.x * 128, N0 = blockIdx.y * 128;
  int wr = wave >> 1, wc = wave & 1;
  f32x4 acc[4][4] = {};

  for (int kt = 0; kt < 16; ++kt) {
    for (int hh = 0; hh < 2; ++hh) {
      int c = wave * 2 + hh;  // chunk: 16 rows of 64B
      const unsigned short* ga = A + (size_t)(M0 + c * 16 + (lane >> 2)) * 512 + kt * 32 + (lane & 3) * 8;
      gload_lds16(ga, As + c * 512);
      const unsigned short* gb = Bt + (size_t)(N0 + c * 16 + (lane >> 2)) * 512 + kt * 32 + (lane & 3) * 8;
      gload_lds16(gb, Bs + c * 512);
    }
    asm volatile("s_waitcnt vmcnt(0)" ::: "memory");
    __syncthreads();
    bf16x8 af[4], bfr[4];
    for (int mf = 0; mf < 4; ++mf)
      af[mf] = *(const bf16x8*)(As + (wr * 64 + mf * 16 + lr) * 32 + lq * 8);
    for (int nf = 0; nf < 4; ++nf)
      bfr[nf] = *(const bf16x8*)(Bs + (wc * 64 + nf * 16 + lr) * 32 + lq * 8);
    for (int mf = 0; mf < 4; ++mf)
      for (int nf = 0; nf < 4; ++nf)
        acc[mf][nf] = __builtin_amdgcn_mfma_f32_16x16x32_bf16(af[mf], bfr[nf], acc[mf][nf], 0, 0, 0);
    __syncthreads();
  }
  // bias (m = M0 + wr*64 + mf*16 + lq*4 + r)
  for (int mf = 0; mf < 4; ++mf) {
    f32x4 bv = *(const f32x4*)(bias + M0 + wr * 64 + mf * 16 + lq * 4);
    for (int nf = 0; nf < 4; ++nf) acc[mf][nf] += bv;
  }

  if (M0 < 1024) {  // q or k block -> transposed store via LDS
    for (int mf = 0; mf < 4; ++mf)
      for (int nf = 0; nf < 4; ++nf) {
        int m = wr * 64 + mf * 16 + lq * 4;
        int n = wc * 64 + nf * 16 + lr;
        ushort4 pk; pk.x = f2bf(acc[mf][nf].x); pk.y = f2bf(acc[mf][nf].y);
        pk.z = f2bf(acc[mf][nf].z); pk.w = f2bf(acc[mf][nf].w);
        *(ushort4*)(Ct + n * 136 + m) = pk;
      }
    __syncthreads();
    int n = tid >> 1, half = tid & 1;
    const unsigned short* src = Ct + n * 136 + half * 64;
    unsigned short* dst = qk_t + (size_t)(N0 + n) * 1024 + M0 + half * 64;
    for (int ch = 0; ch < 8; ++ch)
      *(uint4*)(dst + ch * 8) = *(const uint4*)(src + ch * 8);
  } else {  // v block -> natural layout
    for (int mf = 0; mf < 4; ++mf)
      for (int nf = 0; nf < 4; ++nf) {
        int m = M0 - 1024 + wr * 64 + mf * 16 + lq * 4;
        int n = N0 + wc * 64 + nf * 16 + lr;
        for (int r = 0; r < 4; ++r)
          v_nat[(size_t)(m + r) * NPIX + n] = f2bf(acc[mf][nf][r]);
      }
  }
}

// ---------------- attention: per (h, fixed, itile) block --------------------
// pixels p = fixed*256 + j. Block: 4 waves x 16 queries = 64 queries.
// S^T[j][i] = sum_c K^T[j][c] Q^T[i][c]; softmax over j; O[d][i] = sum_j V[d][j] P^T[j][i]
// PHASE 0: out1 = x + O (fp32, [D][S][L]) + bf16 transposed copy out_bt[p'][512]
// PHASE 1: out_bt[c][p'] = bf16(O)   (p' = fixed*256 + i)
template <int PHASE>
__global__ __launch_bounds__(256) void k_attn(const unsigned short* __restrict__ qk_t,
                                              const unsigned short* __restrict__ v_nat,
                                              const float* __restrict__ x,
                                              float* __restrict__ out1,
                                              unsigned short* __restrict__ out_bt) {
  __shared__ unsigned short smem[32768];      // 64 KiB
  unsigned short* Ks = smem;                  // 32 KiB: K^T [256][64] swz; later P
  unsigned short* Vs = smem + 16384;          // 32 KiB: V   [64][256] swz; later O^T
  int tid = threadIdx.x, lane = tid & 63, wave = tid >> 6;
  int lr = lane & 15, lq = lane >> 4;
  int i0b = blockIdx.x * 64;
  int fix = blockIdx.y;
  int h = blockIdx.z;
  size_t pixbase = (size_t)fix * 256;

  // stage K^T (rows j, 64 ch at col 512+h*64), XOR-swizzled
  {
    int jb = tid >> 3, ch = tid & 7;
    for (int iter = 0; iter < 8; ++iter) {
      int j = iter * 32 + jb;
      uint4 val = *(const uint4*)(qk_t + (pixbase + j) * 1024 + 512 + h * 64 + ch * 8);
      *(uint4*)((char*)Ks + j * 128 + ((ch * 16) ^ ((j & 7) << 4))) = val;
    }
    for (int iter = 0; iter < 8; ++iter) {  // stage V [64 d][256 j]
      int f = iter * 256 + tid, d = f >> 5, ch2 = f & 31;
      uint4 val = *(const uint4*)(v_nat + (size_t)(h * 64 + d) * NPIX + pixbase + ch2 * 8);
      *(uint4*)((char*)Vs + d * 512 + ((ch2 * 16) ^ ((d & 7) << 4))) = val;
    }
  }
  // Q fragments straight from global (B-operand: n=i=lr, k=c contiguous)
  const unsigned short* qp = qk_t + (pixbase + i0b + wave * 16 + lr) * 1024 + h * 64 + lq * 8;
  bf16x8 qf0 = *(const bf16x8*)(qp);
  bf16x8 qf1 = *(const bf16x8*)(qp + 32);
  __syncthreads();

  // S^T = K^T x Q  (lane holds S[j = mf*16 + lq*4 + r][i = lr])
  f32x4 s_acc[16] = {};
  for (int mf = 0; mf < 16; ++mf) {
    int j = mf * 16 + lr;
    const char* krow = (const char*)Ks + j * 128;
    int swz = (j & 7) << 4;
    bf16x8 kf0 = *(const bf16x8*)(krow + ((lq * 16) ^ swz));
    bf16x8 kf1 = *(const bf16x8*)(krow + ((64 + lq * 16) ^ swz));
    s_acc[mf] = __builtin_amdgcn_mfma_f32_16x16x32_bf16(kf0, qf0, s_acc[mf], 0, 0, 0);
    s_acc[mf] = __builtin_amdgcn_mfma_f32_16x16x32_bf16(kf1, qf1, s_acc[mf], 0, 0, 0);
  }
  // softmax over j: 64 in-lane values + xor16 + xor32
  float mx = -3.4e38f;
  for (int mf = 0; mf < 16; ++mf)
    for (int r = 0; r < 4; ++r) mx = fmaxf(mx, s_acc[mf][r]);
  mx = fmaxf(mx, __shfl_xor(mx, 16, 64));
  mx = fmaxf(mx, __shfl_xor(mx, 32, 64));
  float sum = 0.f;
  for (int mf = 0; mf < 16; ++mf)
    for (int r = 0; r < 4; ++r) {
      float p = __expf(s_acc[mf][r] - mx);
      s_acc[mf][r] = p; sum += p;
    }
  sum += __shfl_xor(sum, 16, 64);
  sum += __shfl_xor(sum, 32, 64);
  float inv = 1.f / sum;
  __syncthreads();  // everyone done reading Ks -> overlay P
  {
    char* Pw = (char*)Ks + wave * 8192;       // [16 i][256 j] bf16, swizzled
    int pswz = (lr & 7) << 4;
    for (int mf = 0; mf < 16; ++mf) {
      ushort4 pk;
      pk.x = f2bf(s_acc[mf][0] * inv); pk.y = f2bf(s_acc[mf][1] * inv);
      pk.z = f2bf(s_acc[mf][2] * inv); pk.w = f2bf(s_acc[mf][3] * inv);
      int jb = mf * 32 + lq * 8;              // byte offset of j0 within row
      *(ushort4*)(Pw + lr * 512 + (jb ^ pswz)) = pk;
    }
  }
  // PV: O[d][i] = V x P^T
  f32x4 o_acc[4] = {};
  {
    const char* Pw = (const char*)Ks + wave * 8192;
    int pswz = (lr & 7) << 4;
    for (int ks = 0; ks < 8; ++ks) {
      bf16x8 pb = *(const bf16x8*)(Pw + lr * 512 + ((ks * 64 + lq * 16) ^ pswz));
      for (int mf = 0; mf < 4; ++mf) {
        int d = mf * 16 + lr;
        bf16x8 vf = *(const bf16x8*)((const char*)Vs + d * 512 + ((ks * 64 + lq * 16) ^ ((d & 7) << 4)));
        o_acc[mf] = __builtin_amdgcn_mfma_f32_16x16x32_bf16(vf, pb, o_acc[mf], 0, 0, 0);
      }
    }
  }
  int i_loc = wave * 16 + lr;
  size_t i_glob = (size_t)i0b + i_loc;
  if (PHASE == 0) {
    float vres[4][4];
    for (int mf = 0; mf < 4; ++mf) {
      int dbase = mf * 16 + lq * 4;
      for (int r = 0; r < 4; ++r) {
        size_t off = (size_t)(h * 64 + dbase + r) * NPIX + pixbase + i_glob;
        float val = o_acc[mf][r] + x[off];
        out1[off] = val;
        vres[mf][r] = val;
      }
    }
    __syncthreads();                         // PV reads of Vs done -> overlay O^T
    unsigned short* Obt = Vs;                // [64 i][80 d]
    for (int mf = 0; mf < 4; ++mf) {
      int dbase = mf * 16 + lq * 4;
      ushort4 pk; pk.x = f2bf(vres[mf][0]); pk.y = f2bf(vres[mf][1]);
      pk.z = f2bf(vres[mf][2]); pk.w = f2bf(vres[mf][3]);
      *(ushort4*)(Obt + i_loc * 80 + dbase) = pk;
    }
    __syncthreads();
    int ii = tid >> 2, q = tid & 3;
    unsigned short* dst = out_bt + ((size_t)(i0b + ii) * 256 + fix) * 512 + h * 64 + q * 16;
    const unsigned short* src = Obt + ii * 80 + q * 16;
    *(uint4*)(dst)     = *(const uint4*)(src);
    *(uint4*)(dst + 8) = *(const uint4*)(src + 8);
  } else {
    for (int mf = 0; mf < 4; ++mf) {
      int dbase = mf * 16 + lq * 4;
      for (int r = 0; r < 4; ++r) {
        size_t off = (size_t)(h * 64 + dbase + r) * NPIX + pixbase + i_glob;
        out_bt[off] = f2bf(o_acc[mf][r]);
      }
    }
  }
}

// --------- final: out[c][s][l] += colout_bt[c][l][s] (LDS transpose-add) ----
__global__ __launch_bounds__(256) void k_final(const unsigned short* __restrict__ colt,
                                               float* __restrict__ out) {
  __shared__ unsigned short Xs[64 * 68];
  int c = blockIdx.y;
  int lt = blockIdx.x & 3, st = blockIdx.x >> 2;
  int l0 = lt * 64, s0 = st * 64;
  int t = threadIdx.x;
  for (int rep = 0; rep < 4; ++rep) {
    int f = rep * 256 + t, li = f >> 4, jj = f & 15;
    ushort4 v = *(const ushort4*)(colt + (size_t)c * NPIX + (size_t)(l0 + li) * 256 + s0 + jj * 4);
    *(ushort4*)(Xs + li * 68 + jj * 4) = v;
  }
  __syncthreads();
  int si = t >> 2, q = t & 3;
  float* drow = out + (size_t)c * NPIX + (size_t)(s0 + si) * 256 + l0 + q * 16;
  for (int h4 = 0; h4 < 4; ++h4) {
    float4 a = *(float4*)(drow + h4 * 4);
    a.x += bf2f(Xs[(q * 16 + h4 * 4 + 0) * 68 + si]);
    a.y += bf2f(Xs[(q * 16 + h4 * 4 + 1) * 68 + si]);
    a.z += bf2f(Xs[(q * 16 + h4 * 4 + 2) * 68 + si]);
    a.w += bf2f(Xs[(q * 16 + h4 * 4 + 3) * 68 + si]);
    *(float4*)(drow + h4 * 4) = a;
  }
}

extern "C" void kernel_launch(void* const* d_in, const int* in_sizes, int n_in,
                              void* d_out, int out_size, void* d_ws, size_t ws_size,
                              hipStream_t stream) {
  const float* x  = (const float*)d_in[0];
  const float* Wr = (const float*)d_in[1];
  const float* br = (const float*)d_in[2];
  const float* Wc = (const float*)d_in[3];
  const float* bc = (const float*)d_in[4];
  float* out = (float*)d_out;
  char* ws = (char*)d_ws;
  // workspace layout (~259 MB total)
  unsigned short* qk_t  = (unsigned short*)(ws);                            // 128 MB [65536][1024]
  unsigned short* v_nat = (unsigned short*)(ws + 134217728);                // 64 MB  [512][65536]
  unsigned short* scr3  = (unsigned short*)(ws + 134217728 + 67108864);     // 64 MB  x^T / out1bt / colout
  unsigned short* Wrb   = (unsigned short*)(ws + 268435456);                // 1.5 MB
  unsigned short* Wcb   = (unsigned short*)(ws + 268435456 + 1572864);      // 1.5 MB

  k_cvt<<<768, 256, 0, stream>>>(Wr, Wrb, 196608);
  k_cvt<<<768, 256, 0, stream>>>(Wc, Wcb, 196608);
  k_cvt_transpose<<<dim3(1024, 8), 256, 0, stream>>>(x, scr3);              // scr3 = x^T bf16
  k_gemm<<<dim3(12, 512), 256, 0, stream>>>(Wrb, scr3, br, qk_t, v_nat);    // row QKV
  k_attn<0><<<dim3(4, 256, 8), 256, 0, stream>>>(qk_t, v_nat, x, out, scr3);// out=out1, scr3=out1^T bf16
  k_gemm<<<dim3(12, 512), 256, 0, stream>>>(Wcb, scr3, bc, qk_t, v_nat);    // col QKV
  k_attn<1><<<dim3(4, 256, 8), 256, 0, stream>>>(qk_t, v_nat, nullptr, nullptr, scr3); // scr3=colout
  k_final<<<dim3(16, 512), 256, 0, stream>>>(scr3, out);                    // out += colout^T
}

// Round 2
// 638.128 us; speedup vs baseline: 1.1765x; 1.1765x over previous
//
#include <hip/hip_runtime.h>

typedef __bf16 bf16_t;
typedef __attribute__((ext_vector_type(8))) __bf16 bf16x8;
typedef __attribute__((ext_vector_type(4))) float f32x4;

#define NH   8
#define DH   64
#define DD   512
#define NPIX 65536   // 256*256

__device__ __forceinline__ unsigned short f2bf(float f) {
  unsigned int u = __builtin_bit_cast(unsigned int, f);
  u += 0x7fffu + ((u >> 16) & 1u);
  return (unsigned short)(u >> 16);
}
__device__ __forceinline__ float bf2f(unsigned short b) {
  return __builtin_bit_cast(float, ((unsigned int)b) << 16);
}

__device__ __forceinline__ void gload_lds16(const void* g, void* l) {
  __builtin_amdgcn_global_load_lds(
      (const __attribute__((address_space(1))) void*)(uintptr_t)g,
      (__attribute__((address_space(3))) void*)(uintptr_t)l, 16, 0, 0);
}

// ---------------- elementwise fp32 -> bf16 convert (weights) ----------------
__global__ __launch_bounds__(256) void k_cvt(const float* __restrict__ in,
                                             unsigned short* __restrict__ out, int n4) {
  int i = blockIdx.x * 256 + threadIdx.x;
  if (i >= n4) return;
  float4 v = ((const float4*)in)[i];
  ushort4 o; o.x = f2bf(v.x); o.y = f2bf(v.y); o.z = f2bf(v.z); o.w = f2bf(v.w);
  ((ushort4*)out)[i] = o;
}

// ------------- x [512][65536] f32 -> x^T [65536][512] bf16 ------------------
__global__ __launch_bounds__(256) void k_cvt_transpose(const float* __restrict__ x,
                                                       unsigned short* __restrict__ xt) {
  __shared__ unsigned short Xs[64 * 68];
  int p0 = blockIdx.x * 64, c0 = blockIdx.y * 64;
  int t = threadIdx.x;
  for (int rep = 0; rep < 4; ++rep) {
    int f = rep * 256 + t, i = f >> 4, jj = f & 15;
    float4 v = *(const float4*)(x + (size_t)(c0 + i) * NPIX + p0 + jj * 4);
    ushort4 o; o.x = f2bf(v.x); o.y = f2bf(v.y); o.z = f2bf(v.z); o.w = f2bf(v.w);
    *(ushort4*)(Xs + i * 68 + jj * 4) = o;
  }
  __syncthreads();
  int j = t >> 2, q = t & 3;
  unsigned short* dst = xt + (size_t)(p0 + j) * DD + c0 + q * 16;
  for (int h2 = 0; h2 < 2; ++h2) {
    union { unsigned short u[8]; uint4 v; } pk;
    for (int cc = 0; cc < 8; ++cc) pk.u[cc] = Xs[(q * 16 + h2 * 8 + cc) * 68 + j];
    *(uint4*)(dst + h2 * 8) = pk.v;
  }
}

// ---------------- GEMM: C[1536][65536] = W[1536][512] @ X + b ---------------
// 256x256 tile, BK=64, 8 waves (2Mx4N), 2-phase double-buffered staging.
// A: W bf16 [M][K] row-major. Bt: X^T bf16 [N][K] row-major.
// Output: rows 0..1023 (q,k) TRANSPOSED into qk_t[p][1024];
//         rows 1024..1535 (v) natural into v_nat[d][p].
__global__ __launch_bounds__(512, 2) void k_gemm(const unsigned short* __restrict__ A,
                                                 const unsigned short* __restrict__ Bt,
                                                 const float* __restrict__ bias,
                                                 unsigned short* __restrict__ qk_t,
                                                 unsigned short* __restrict__ v_nat) {
  __shared__ unsigned short smem[65536];  // 128 KiB: 2 x (A 256x64 + B 256x64) bf16
  int tid = threadIdx.x, lane = tid & 63, wave = tid >> 6;
  int lr = lane & 15, lq = lane >> 4;
  // T1: bijective XCD swizzle over 1536 blocks (1536 % 8 == 0)
  int bid = blockIdx.y * 6 + blockIdx.x;
  int lid = (bid & 7) * 192 + (bid >> 3);
  int M0 = (lid % 6) * 256;
  size_t N0 = (size_t)(lid / 6) * 256;
  int wr = wave >> 2, wc = wave & 3;   // 2 x 4 wave grid; wave tile 128x64
  f32x4 acc[8][4] = {};

  const unsigned short* Abase = A + (size_t)M0 * 512;
  const unsigned short* Bbase = Bt + N0 * 512;

  // stage tile kt into buffer b. LDS linear [256 rows][64 cols] bf16 (128B rows);
  // T2: source chunk pre-swizzled so reads can XOR ((row&7)<<4) conflict-free.
  auto STAGE = [&](int b, int kt) {
#pragma unroll
    for (int it = 0; it < 4; ++it) {
      int f = it * 512 + tid;
      int row = f >> 3;
      int cc = (f & 7) ^ (row & 7);
      const unsigned short* ga = Abase + (size_t)row * 512 + kt * 64 + cc * 8;
      gload_lds16(ga, smem + b * 32768 + f * 8);
      const unsigned short* gb = Bbase + (size_t)row * 512 + kt * 64 + cc * 8;
      gload_lds16(gb, smem + b * 32768 + 16384 + f * 8);
    }
  };

  STAGE(0, 0);
  asm volatile("s_waitcnt vmcnt(0)" ::: "memory");
  __syncthreads();
  int cur = 0;
  for (int kt = 0; kt < 8; ++kt) {
    if (kt < 7) STAGE(cur ^ 1, kt + 1);   // prefetch next tile (in flight over compute)
    const char* Ad = (const char*)(smem + cur * 32768);
    const char* Bd = Ad + 32768;
#pragma unroll
    for (int ks = 0; ks < 2; ++ks) {
      bf16x8 af[8], bfr[4];
#pragma unroll
      for (int mf = 0; mf < 8; ++mf) {
        int r = wr * 128 + mf * 16 + lr;
        int c = ks * 64 + lq * 16;
        af[mf] = *(const bf16x8*)(Ad + r * 128 + (c ^ ((r & 7) << 4)));
      }
#pragma unroll
      for (int nf = 0; nf < 4; ++nf) {
        int r = wc * 64 + nf * 16 + lr;
        int c = ks * 64 + lq * 16;
        bfr[nf] = *(const bf16x8*)(Bd + r * 128 + (c ^ ((r & 7) << 4)));
      }
      __builtin_amdgcn_s_setprio(1);
#pragma unroll
      for (int mf = 0; mf < 8; ++mf)
#pragma unroll
        for (int nf = 0; nf < 4; ++nf)
          acc[mf][nf] = __builtin_amdgcn_mfma_f32_16x16x32_bf16(af[mf], bfr[nf], acc[mf][nf], 0, 0, 0);
      __builtin_amdgcn_s_setprio(0);
    }
    asm volatile("s_waitcnt vmcnt(0)" ::: "memory");  // next tile landed
    __syncthreads();
    cur ^= 1;
  }

  // bias add: C row m = M0 + wr*128 + mf*16 + lq*4 + r
#pragma unroll
  for (int mf = 0; mf < 8; ++mf) {
    f32x4 bv = *(const f32x4*)(bias + M0 + wr * 128 + mf * 16 + lq * 4);
#pragma unroll
    for (int nf = 0; nf < 4; ++nf) acc[mf][nf] += bv;
  }

  if (M0 < 1024) {
    // q/k: transposed store via LDS, two n-halves. Ct[128 n][264 m-stride]
    unsigned short* Ct = smem;
    for (int h2 = 0; h2 < 2; ++h2) {
      __syncthreads();
      if ((wc >> 1) == h2) {
        int ncb = (wc & 1) * 64;
#pragma unroll
        for (int mf = 0; mf < 8; ++mf)
#pragma unroll
          for (int nf = 0; nf < 4; ++nf) {
            int n = ncb + nf * 16 + lr;
            int m = wr * 128 + mf * 16 + lq * 4;
            ushort4 pk;
            pk.x = f2bf(acc[mf][nf].x); pk.y = f2bf(acc[mf][nf].y);
            pk.z = f2bf(acc[mf][nf].z); pk.w = f2bf(acc[mf][nf].w);
            *(ushort4*)(Ct + n * 264 + m) = pk;
          }
      }
      __syncthreads();
      int n = tid >> 2, q = tid & 3;
      const unsigned short* src = Ct + n * 264 + q * 64;
      unsigned short* dst = qk_t + (N0 + h2 * 128 + n) * 1024 + M0 + q * 64;
#pragma unroll
      for (int ch = 0; ch < 8; ++ch)
        *(uint4*)(dst + ch * 8) = *(const uint4*)(src + ch * 8);
    }
  } else {
    // v: natural layout, scalar stores (16 lanes -> 32B contiguous, L2 combines)
#pragma unroll
    for (int mf = 0; mf < 8; ++mf)
#pragma unroll
      for (int nf = 0; nf < 4; ++nf) {
        int m = M0 - 1024 + wr * 128 + mf * 16 + lq * 4;
        size_t n = N0 + wc * 64 + nf * 16 + lr;
#pragma unroll
        for (int r = 0; r < 4; ++r)
          v_nat[(size_t)(m + r) * NPIX + n] = f2bf(acc[mf][nf][r]);
      }
  }
}

// ---------------- attention: per (h, fixed, itile) block --------------------
// pixels p = fixed*256 + j. Block: 4 waves x 16 queries = 64 queries.
// S^T[j][i] = sum_c K^T[j][c] Q^T[i][c]; softmax over j; O[d][i] = sum_j V[d][j] P^T[j][i]
// PHASE 0: out1 = x + O (fp32, [D][S][L]) + bf16 transposed copy out_bt[p'][512]
// PHASE 1: out_bt[c][p'] = bf16(O)   (p' = fixed*256 + i)
template <int PHASE>
__global__ __launch_bounds__(256) void k_attn(const unsigned short* __restrict__ qk_t,
                                              const unsigned short* __restrict__ v_nat,
                                              const float* __restrict__ x,
                                              float* __restrict__ out1,
                                              unsigned short* __restrict__ out_bt) {
  __shared__ unsigned short smem[32768];      // 64 KiB
  unsigned short* Ks = smem;                  // 32 KiB: K^T [256][64] swz; later P
  unsigned short* Vs = smem + 16384;          // 32 KiB: V   [64][256] swz; later O^T
  int tid = threadIdx.x, lane = tid & 63, wave = tid >> 6;
  int lr = lane & 15, lq = lane >> 4;
  int i0b = blockIdx.x * 64;
  int fix = blockIdx.y;
  int h = blockIdx.z;
  size_t pixbase = (size_t)fix * 256;

  // stage K^T (rows j, 64 ch at col 512+h*64), XOR-swizzled
  {
    int jb = tid >> 3, ch = tid & 7;
    for (int iter = 0; iter < 8; ++iter) {
      int j = iter * 32 + jb;
      uint4 val = *(const uint4*)(qk_t + (pixbase + j) * 1024 + 512 + h * 64 + ch * 8);
      *(uint4*)((char*)Ks + j * 128 + ((ch * 16) ^ ((j & 7) << 4))) = val;
    }
    for (int iter = 0; iter < 8; ++iter) {  // stage V [64 d][256 j]
      int f = iter * 256 + tid, d = f >> 5, ch2 = f & 31;
      uint4 val = *(const uint4*)(v_nat + (size_t)(h * 64 + d) * NPIX + pixbase + ch2 * 8);
      *(uint4*)((char*)Vs + d * 512 + ((ch2 * 16) ^ ((d & 7) << 4))) = val;
    }
  }
  // Q fragments straight from global (B-operand: n=i=lr, k=c contiguous)
  const unsigned short* qp = qk_t + (pixbase + i0b + wave * 16 + lr) * 1024 + h * 64 + lq * 8;
  bf16x8 qf0 = *(const bf16x8*)(qp);
  bf16x8 qf1 = *(const bf16x8*)(qp + 32);
  __syncthreads();

  // S^T = K^T x Q  (lane holds S[j = mf*16 + lq*4 + r][i = lr])
  f32x4 s_acc[16] = {};
  for (int mf = 0; mf < 16; ++mf) {
    int j = mf * 16 + lr;
    const char* krow = (const char*)Ks + j * 128;
    int swz = (j & 7) << 4;
    bf16x8 kf0 = *(const bf16x8*)(krow + ((lq * 16) ^ swz));
    bf16x8 kf1 = *(const bf16x8*)(krow + ((64 + lq * 16) ^ swz));
    s_acc[mf] = __builtin_amdgcn_mfma_f32_16x16x32_bf16(kf0, qf0, s_acc[mf], 0, 0, 0);
    s_acc[mf] = __builtin_amdgcn_mfma_f32_16x16x32_bf16(kf1, qf1, s_acc[mf], 0, 0, 0);
  }
  // softmax over j: 64 in-lane values + xor16 + xor32
  float mx = -3.4e38f;
  for (int mf = 0; mf < 16; ++mf)
    for (int r = 0; r < 4; ++r) mx = fmaxf(mx, s_acc[mf][r]);
  mx = fmaxf(mx, __shfl_xor(mx, 16, 64));
  mx = fmaxf(mx, __shfl_xor(mx, 32, 64));
  float sum = 0.f;
  for (int mf = 0; mf < 16; ++mf)
    for (int r = 0; r < 4; ++r) {
      float p = __expf(s_acc[mf][r] - mx);
      s_acc[mf][r] = p; sum += p;
    }
  sum += __shfl_xor(sum, 16, 64);
  sum += __shfl_xor(sum, 32, 64);
  float inv = 1.f / sum;
  __syncthreads();  // everyone done reading Ks -> overlay P
  {
    char* Pw = (char*)Ks + wave * 8192;       // [16 i][256 j] bf16, swizzled
    int pswz = (lr & 7) << 4;
    for (int mf = 0; mf < 16; ++mf) {
      ushort4 pk;
      pk.x = f2bf(s_acc[mf][0] * inv); pk.y = f2bf(s_acc[mf][1] * inv);
      pk.z = f2bf(s_acc[mf][2] * inv); pk.w = f2bf(s_acc[mf][3] * inv);
      int jb = mf * 32 + lq * 8;              // byte offset of j0 within row
      *(ushort4*)(Pw + lr * 512 + (jb ^ pswz)) = pk;
    }
  }
  // PV: O[d][i] = V x P^T
  f32x4 o_acc[4] = {};
  {
    const char* Pw = (const char*)Ks + wave * 8192;
    int pswz = (lr & 7) << 4;
    for (int ks = 0; ks < 8; ++ks) {
      bf16x8 pb = *(const bf16x8*)(Pw + lr * 512 + ((ks * 64 + lq * 16) ^ pswz));
      for (int mf = 0; mf < 4; ++mf) {
        int d = mf * 16 + lr;
        bf16x8 vf = *(const bf16x8*)((const char*)Vs + d * 512 + ((ks * 64 + lq * 16) ^ ((d & 7) << 4)));
        o_acc[mf] = __builtin_amdgcn_mfma_f32_16x16x32_bf16(vf, pb, o_acc[mf], 0, 0, 0);
      }
    }
  }
  int i_loc = wave * 16 + lr;
  size_t i_glob = (size_t)i0b + i_loc;
  if (PHASE == 0) {
    float vres[4][4];
    for (int mf = 0; mf < 4; ++mf) {
      int dbase = mf * 16 + lq * 4;
      for (int r = 0; r < 4; ++r) {
        size_t off = (size_t)(h * 64 + dbase + r) * NPIX + pixbase + i_glob;
        float val = o_acc[mf][r] + x[off];
        out1[off] = val;
        vres[mf][r] = val;
      }
    }
    __syncthreads();                         // PV reads of Vs done -> overlay O^T
    unsigned short* Obt = Vs;                // [64 i][80 d]
    for (int mf = 0; mf < 4; ++mf) {
      int dbase = mf * 16 + lq * 4;
      ushort4 pk; pk.x = f2bf(vres[mf][0]); pk.y = f2bf(vres[mf][1]);
      pk.z = f2bf(vres[mf][2]); pk.w = f2bf(vres[mf][3]);
      *(ushort4*)(Obt + i_loc * 80 + dbase) = pk;
    }
    __syncthreads();
    int ii = tid >> 2, q = tid & 3;
    unsigned short* dst = out_bt + ((size_t)(i0b + ii) * 256 + fix) * 512 + h * 64 + q * 16;
    const unsigned short* src = Obt + ii * 80 + q * 16;
    *(uint4*)(dst)     = *(const uint4*)(src);
    *(uint4*)(dst + 8) = *(const uint4*)(src + 8);
  } else {
    for (int mf = 0; mf < 4; ++mf) {
      int dbase = mf * 16 + lq * 4;
      for (int r = 0; r < 4; ++r) {
        size_t off = (size_t)(h * 64 + dbase + r) * NPIX + pixbase + i_glob;
        out_bt[off] = f2bf(o_acc[mf][r]);
      }
    }
  }
}

// --------- final: out[c][s][l] += colout_bt[c][l][s] (LDS transpose-add) ----
__global__ __launch_bounds__(256) void k_final(const unsigned short* __restrict__ colt,
                                               float* __restrict__ out) {
  __shared__ unsigned short Xs[64 * 68];
  int c = blockIdx.y;
  int lt = blockIdx.x & 3, st = blockIdx.x >> 2;
  int l0 = lt * 64, s0 = st * 64;
  int t = threadIdx.x;
  for (int rep = 0; rep < 4; ++rep) {
    int f = rep * 256 + t, li = f >> 4, jj = f & 15;
    ushort4 v = *(const ushort4*)(colt + (size_t)c * NPIX + (size_t)(l0 + li) * 256 + s0 + jj * 4);
    *(ushort4*)(Xs + li * 68 + jj * 4) = v;
  }
  __syncthreads();
  int si = t >> 2, q = t & 3;
  float* drow = out + (size_t)c * NPIX + (size_t)(s0 + si) * 256 + l0 + q * 16;
  for (int h4 = 0; h4 < 4; ++h4) {
    float4 a = *(float4*)(drow + h4 * 4);
    a.x += bf2f(Xs[(q * 16 + h4 * 4 + 0) * 68 + si]);
    a.y += bf2f(Xs[(q * 16 + h4 * 4 + 1) * 68 + si]);
    a.z += bf2f(Xs[(q * 16 + h4 * 4 + 2) * 68 + si]);
    a.w += bf2f(Xs[(q * 16 + h4 * 4 + 3) * 68 + si]);
    *(float4*)(drow + h4 * 4) = a;
  }
}

extern "C" void kernel_launch(void* const* d_in, const int* in_sizes, int n_in,
                              void* d_out, int out_size, void* d_ws, size_t ws_size,
                              hipStream_t stream) {
  const float* x  = (const float*)d_in[0];
  const float* Wr = (const float*)d_in[1];
  const float* br = (const float*)d_in[2];
  const float* Wc = (const float*)d_in[3];
  const float* bc = (const float*)d_in[4];
  float* out = (float*)d_out;
  char* ws = (char*)d_ws;
  // workspace layout (~259 MB total)
  unsigned short* qk_t  = (unsigned short*)(ws);                            // 128 MB [65536][1024]
  unsigned short* v_nat = (unsigned short*)(ws + 134217728);                // 64 MB  [512][65536]
  unsigned short* scr3  = (unsigned short*)(ws + 134217728 + 67108864);     // 64 MB  x^T / out1bt / colout
  unsigned short* Wrb   = (unsigned short*)(ws + 268435456);                // 1.5 MB
  unsigned short* Wcb   = (unsigned short*)(ws + 268435456 + 1572864);      // 1.5 MB

  k_cvt<<<768, 256, 0, stream>>>(Wr, Wrb, 196608);
  k_cvt<<<768, 256, 0, stream>>>(Wc, Wcb, 196608);
  k_cvt_transpose<<<dim3(1024, 8), 256, 0, stream>>>(x, scr3);              // scr3 = x^T bf16
  k_gemm<<<dim3(6, 256), 512, 0, stream>>>(Wrb, scr3, br, qk_t, v_nat);     // row QKV
  k_attn<0><<<dim3(4, 256, 8), 256, 0, stream>>>(qk_t, v_nat, x, out, scr3);// out=out1, scr3=out1^T bf16
  k_gemm<<<dim3(6, 256), 512, 0, stream>>>(Wcb, scr3, bc, qk_t, v_nat);     // col QKV
  k_attn<1><<<dim3(4, 256, 8), 256, 0, stream>>>(qk_t, v_nat, nullptr, nullptr, scr3); // scr3=colout
  k_final<<<dim3(16, 512), 256, 0, stream>>>(scr3, out);                    // out += colout^T
}